// Round 6
// baseline (56824.982 us; speedup 1.0000x reference)
//
#include <hip/hip_runtime.h>
#include <hip/hip_bf16.h>
#include <cstddef>
#include <cstdint>

// B=32, T=2048, D=64, H=256, O=32, 4H=1024
#define BB 32
#define TT 2048
#define DD 64
#define HH 256
#define OO 32

#define OUT_ELEMS (BB*TT*OO)
#define HN_OFF OUT_ELEMS
#define CN_OFF (HN_OFF + 2*BB*HH)

// ---------------- workspace byte offsets ----------------
#define O_XBF   ((size_t)0)            // x bf16 [T][B][64]           8,388,608
#define O_Y0G   ((size_t)8388608)      // y0 bf16 [T][B][256]        33,554,432
#define O_Y1G   ((size_t)41943040)     // y1 bf16 [T][B][256]        33,554,432
#define O_WP0   ((size_t)75497472)     // Wperm0 bf16 [1024][320]       655,360
#define O_WP1   ((size_t)76152832)     // Wperm1 bf16 [1024][512]     1,048,576
#define O_B0    ((size_t)77201408)     // bias0 f32 [1024]
#define O_B1    ((size_t)77205504)     // bias1 f32 [1024]
#define O_WD0T  ((size_t)77209600)     // [256][256] f32 transposed
#define O_WD1T  ((size_t)77471744)
#define O_WOUT  ((size_t)77733888)     // [256][32] f32
#define O_FLG   ((size_t)77766656)     // flags: group g at int offset g*64

#define ROWP 264   // LDS row pitch in bf16 elems (16B-aligned rows, ~2-way banks)

typedef short short8 __attribute__((ext_vector_type(8)));
typedef float f32x4 __attribute__((ext_vector_type(4)));
typedef unsigned long long ull;

__device__ __forceinline__ float sigm_(float x){ return 1.0f/(1.0f+__expf(-x)); }
__device__ __forceinline__ float tanhf_(float x){
    float xc = fminf(fmaxf(x, -15.0f), 15.0f);
    float e = __expf(2.0f*xc);
    return (e-1.0f)/(e+1.0f);
}
__device__ __forceinline__ unsigned short f2bf(float f){
    __hip_bfloat16 h = __float2bfloat16(f);
    return *reinterpret_cast<unsigned short*>(&h);
}
__device__ __forceinline__ unsigned int pack2(float a, float b){
    return (unsigned int)f2bf(a) | ((unsigned int)f2bf(b) << 16);
}
__device__ __forceinline__ short8 ld8(const unsigned short* p){
    return *reinterpret_cast<const short8*>(p);
}

// Wave-level flag wait with cached value: lane0 loads (agent scope = LLC-fresh),
// broadcast, sleep backoff.  Returns the (monotone) observed value so callers
// cache it and skip future polls entirely.  Capped: a bug fails validation.
__device__ __forceinline__ int waitFlag(const int* p, int tgt, int known, int lane){
    int it = 0;
    while (known < tgt) {
        int v = 0;
        if (lane == 0) v = __hip_atomic_load(p, __ATOMIC_RELAXED, __HIP_MEMORY_SCOPE_AGENT);
        v = __shfl(v, 0, 64);
        if (v > known) known = v;
        if (known >= tgt) break;
        __builtin_amdgcn_s_sleep(4);
        if (++it > (1<<16)) break;
    }
    asm volatile("" ::: "memory");
    return known;
}

// ---------------------------------------------------------------------------
// Prep: x->bf16 transpose, weight-row permutation for the 4-gate packed
// A-fragments, bias sums, head-weight transposes, flag zeroing.
//   Row R: lrow=R&15, s=(R>>4)&1, o=(R>>5)&1, w=R>>6
//   gate = 2s+(lrow>>3), h = 16w+8o+(lrow&7), src_row = 256*gate+h
// total = 4194304+327680+524288+1024+1024+65536+65536+8192+1024 = 5,188,608
// ---------------------------------------------------------------------------
__global__ void prep_kernel(const float* __restrict__ x,
    const float* __restrict__ Wih0, const float* __restrict__ Whh0,
    const float* __restrict__ bih0, const float* __restrict__ bhh0,
    const float* __restrict__ Wih1, const float* __restrict__ Whh1,
    const float* __restrict__ bih1, const float* __restrict__ bhh1,
    const float* __restrict__ Wd0, const float* __restrict__ Wd1,
    const float* __restrict__ Wout, char* __restrict__ ws)
{
    int i = blockIdx.x*256 + threadIdx.x;
    if (i < 4194304) {  // x [B][T][D] -> [T][B][D] bf16
        int t = i >> 11, rem = i & 2047, b = rem >> 6, d = rem & 63;
        ((unsigned short*)(ws+O_XBF))[i] = f2bf(x[(size_t)b*131072 + t*64 + d]);
        return;
    }
    i -= 4194304;
    if (i < 327680) {   // Wperm0 [1024][320]
        int R = i / 320, k = i - R*320;
        int lrow = R & 15, s = (R>>4)&1, o = (R>>5)&1, w = R>>6;
        int gate = 2*s + (lrow>>3);
        int h = 16*w + 8*o + (lrow&7);
        int src = 256*gate + h;
        float v = (k < 64) ? Wih0[src*64 + k] : Whh0[src*256 + (k-64)];
        ((unsigned short*)(ws+O_WP0))[i] = f2bf(v);
        return;
    }
    i -= 327680;
    if (i < 524288) {   // Wperm1 [1024][512]
        int R = i >> 9, k = i & 511;
        int lrow = R & 15, s = (R>>4)&1, o = (R>>5)&1, w = R>>6;
        int gate = 2*s + (lrow>>3);
        int h = 16*w + 8*o + (lrow&7);
        int src = 256*gate + h;
        float v = (k < 256) ? Wih1[src*256 + k] : Whh1[src*256 + (k-256)];
        ((unsigned short*)(ws+O_WP1))[i] = f2bf(v);
        return;
    }
    i -= 524288;
    if (i < 1024) { ((float*)(ws+O_B0))[i] = bih0[i] + bhh0[i]; return; }
    i -= 1024;
    if (i < 1024) { ((float*)(ws+O_B1))[i] = bih1[i] + bhh1[i]; return; }
    i -= 1024;
    if (i < 65536) { int o = i & 255, h = i >> 8; ((float*)(ws+O_WD0T))[i] = Wd0[o*256 + h]; return; }
    i -= 65536;
    if (i < 65536) { int o = i & 255, h = i >> 8; ((float*)(ws+O_WD1T))[i] = Wd1[o*256 + h]; return; }
    i -= 65536;
    if (i < 8192) { int o = i & 31, h = i >> 5; ((float*)(ws+O_WOUT))[i] = Wout[o*256 + h]; return; }
    i -= 8192;
    if (i < 1024) { ((int*)(ws+O_FLG))[i] = 0; return; }
}

// ---------------------------------------------------------------------------
// Batch-split persistent LSTM.  4 blocks x 1024 threads (16 waves):
//   block = (layer L, batch-group g of 16).  Wave w owns ALL 4 gates for
//   h in [16w,16w+16) (2 octets) x the block's 16 batches.  Full layer
//   weights pinned in VGPRs (L1: 256 VGPR/lane).  h-state lives in LDS
//   (double-buffered) -> ZERO intra-layer cross-block sync.  Only L0->L1
//   y0 handoff goes through LLC, one-directional, flag value cached so
//   steady-state has no polls.  One __syncthreads per step.
// mfma_f32_16x16x32_bf16: A lane l -> A[row=l&15][k=(l>>4)*8+j];
//                         B lane l -> B[k][col=l&15];
//                         D lane l -> D[row=(l>>4)*4+r][col=l&15].
// ---------------------------------------------------------------------------
template<int L>
__device__ void lstm_body(int g, char* ws,
                          const float* __restrict__ h0f, const float* __restrict__ c0f,
                          float* __restrict__ out,
                          unsigned short (*h_lds)[16][ROWP],
                          unsigned short (*s_lds)[16][ROWP])
{
    constexpr int KK  = L ? 512 : 320;
    constexpr int NKT = KK / 32;       // 16 or 10 k-tiles
    constexpr int NS  = L ? 8 : 2;     // k-tiles sourced from s_lds (y0 / x)

    const int tid  = threadIdx.x;
    const int wv   = tid >> 6;
    const int lane = tid & 63;
    const int lrow = lane & 15;        // B-frag col = batch (local) = combine col
    const int q    = lane >> 4;
    const int qe   = q & 1;
    const int koff = q * 8;
    const bool lo  = lane < 32;
    const int hb   = 16 * wv;          // wave's h-slice base

    const unsigned short* Wp   = (const unsigned short*)(ws + (L ? O_WP1 : O_WP0));
    const float* bias          = (const float*)(ws + (L ? O_B1 : O_B0));
    const unsigned short* xbf  = (const unsigned short*)(ws + O_XBF);
    const ull* y0g_r           = (const ull*)(ws + O_Y0G);
    int* flagg                 = (int*)(ws + O_FLG) + g * 64;

    // ---- A fragments: [oct][s: if/go][k-tile], pinned for all 2048 steps ----
    short8 a[2][2][NKT];
#pragma unroll
    for (int o = 0; o < 2; ++o)
#pragma unroll
    for (int s = 0; s < 2; ++s)
#pragma unroll
    for (int kk = 0; kk < NKT; ++kk)
        a[o][s][kk] = ld8(Wp + (size_t)(wv*64 + o*32 + s*16 + lrow)*KK + kk*32 + koff);

    // ---- combine state (duplicated lo/hi halves, as validated r2-r5) ----
    float bI[2][4], bF[2][4], bG[2][4], bO[2][4], c[2][4], hv[2][4];
#pragma unroll
    for (int o = 0; o < 2; ++o)
#pragma unroll
    for (int r = 0; r < 4; ++r) {
        int hg = hb + 8*o + 4*qe + r;
        bI[o][r] = bias[hg];      bF[o][r] = bias[256+hg];
        bG[o][r] = bias[512+hg];  bO[o][r] = bias[768+hg];
        c[o][r]  = c0f[(size_t)L*8192 + (g*16+lrow)*256 + hg];
        hv[o][r] = 0.f;
    }

    // ---- init h_lds[0] from h0 (f32 -> bf16) ----
    {
        int b = tid >> 6, h4 = (tid & 63) * 4;
#pragma unroll
        for (int r = 0; r < 4; ++r)
            h_lds[0][b][h4+r] = f2bf(h0f[(size_t)L*8192 + (g*16+b)*256 + h4+r]);
    }

    const int sb = tid >> 6, sc = tid & 63;   // staging identity
    int known = 0;

    // ---- prologue: stage step-0 input into s_lds[0] ----
    if (L == 0) {
        s_lds[0][sb][sc] = xbf[((size_t)g*16 + sb)*64 + sc];
    } else {
        known = waitFlag(flagg, 1, known, lane);
        ull v = y0g_r[((size_t)g*16 + sb)*64 + sc];
        *(ull*)&s_lds[0][sb][sc*4] = v;
    }
    __syncthreads();

    for (int t = 0; t < TT; ++t) {
        const int cur = t & 1, nxt = cur ^ 1;

        // (a) opportunistic stage-load for t+1 (hoisted above MFMA phase)
        ull sv = 0; unsigned short sx = 0; bool staged = false;
        if (L == 0) {
            if (t+1 < TT) { sx = xbf[((size_t)(t+1)*32 + g*16 + sb)*64 + sc]; staged = true; }
        } else {
            if (t+1 < TT && known >= t+2) {
                sv = y0g_r[((size_t)(t+1)*32 + g*16 + sb)*64 + sc];
                staged = true;
            }
        }

        // (b) MFMA: B-frags from s_lds (x / y0) then h_lds, shared by 4 accs
        f32x4 A00 = {0,0,0,0}, A01 = {0,0,0,0}, A10 = {0,0,0,0}, A11 = {0,0,0,0};
#pragma unroll
        for (int kk = 0; kk < NKT; ++kk) {
            const unsigned short* src = (kk < NS)
                ? &s_lds[cur][lrow][kk*32 + koff]
                : &h_lds[cur][lrow][(kk-NS)*32 + koff];
            short8 bf = ld8(src);
            A00 = __builtin_amdgcn_mfma_f32_16x16x32_bf16(a[0][0][kk], bf, A00, 0,0,0);
            A01 = __builtin_amdgcn_mfma_f32_16x16x32_bf16(a[0][1][kk], bf, A01, 0,0,0);
            A10 = __builtin_amdgcn_mfma_f32_16x16x32_bf16(a[1][0][kk], bf, A10, 0,0,0);
            A11 = __builtin_amdgcn_mfma_f32_16x16x32_bf16(a[1][1][kk], bf, A11, 0,0,0);
        }

        // (c) register combine (shfl_xor 32 pairs (i,f),(g,o)) per octet
#pragma unroll
        for (int o = 0; o < 2; ++o) {
            f32x4 A0 = o ? A10 : A00;
            f32x4 A1 = o ? A11 : A01;
#pragma unroll
            for (int r = 0; r < 4; ++r) {
                float x0 = A0[r], y0s = __shfl_xor(x0, 32, 64);
                float x1 = A1[r], y1s = __shfl_xor(x1, 32, 64);
                float gi = (lo ? x0 : y0s) + bI[o][r];
                float gf = (lo ? y0s : x0) + bF[o][r];
                float gg = (lo ? x1 : y1s) + bG[o][r];
                float go = (lo ? y1s : x1) + bO[o][r];
                float iv = sigm_(gi), fv = sigm_(gf), gv = tanhf_(gg), ov = sigm_(go);
                c[o][r]  = fv*c[o][r] + iv*gv;
                hv[o][r] = ov * tanhf_(c[o][r]);
            }
        }

        // (d) stores: h into LDS[nxt]; y0 -> LLC (sc1) / y1 -> global
        if (lo) {
#pragma unroll
            for (int o = 0; o < 2; ++o) {
                ull w = (ull)pack2(hv[o][0], hv[o][1]) |
                        ((ull)pack2(hv[o][2], hv[o][3]) << 32);
                int hoff = hb + 8*o + 4*qe;
                *(ull*)&h_lds[nxt][lrow][hoff] = w;
                size_t gidx = (((size_t)t*32 + g*16 + lrow)*256 + hoff) >> 2;
                if (L == 0)
                    __hip_atomic_store((ull*)(ws + O_Y0G) + gidx, w,
                                       __ATOMIC_RELAXED, __HIP_MEMORY_SCOPE_AGENT);
                else
                    ((ull*)(ws + O_Y1G))[gidx] = w;
            }
        }

        // (e) finish staging into s_lds[nxt]
        if (L == 0) {
            if (staged) s_lds[nxt][sb][sc] = sx;
        } else if (t+1 < TT) {
            if (!staged) {
                known = waitFlag(flagg, t+2, known, lane);
                sv = y0g_r[((size_t)(t+1)*32 + g*16 + sb)*64 + sc];
            }
            *(ull*)&s_lds[nxt][sb][sc*4] = sv;
        }

        // (f) one barrier per step (drains vmcnt incl. sc1 y0 stores)
        __syncthreads();
        if (L == 0 && tid == 0)
            __hip_atomic_store(flagg, t+1, __ATOMIC_RELAXED, __HIP_MEMORY_SCOPE_AGENT);
    }

    // epilogue: h_n / c_n (f32)
    if (lo) {
#pragma unroll
        for (int o = 0; o < 2; ++o)
#pragma unroll
        for (int r = 0; r < 4; ++r) {
            int hg = hb + 8*o + 4*qe + r;
            out[HN_OFF + (size_t)L*8192 + (g*16+lrow)*256 + hg] = hv[o][r];
            out[CN_OFF + (size_t)L*8192 + (g*16+lrow)*256 + hg] = c[o][r];
        }
    }
}

__global__ __launch_bounds__(1024, 1) void lstm_fused(char* ws,
                                                      const float* __restrict__ h0f,
                                                      const float* __restrict__ c0f,
                                                      float* __restrict__ out)
{
    __shared__ unsigned short h_lds[2][16][ROWP];
    __shared__ unsigned short s_lds[2][16][ROWP];
    const int L = blockIdx.x >> 1, g = blockIdx.x & 1;
    if (L == 0) lstm_body<0>(g, ws, h0f, c0f, out, h_lds, s_lds);
    else        lstm_body<1>(g, ws, h0f, c0f, out, h_lds, s_lds);
}

// ---------------------------------------------------------------------------
// Fused dense head (reads y1g bf16 [t][b][256]).
// ---------------------------------------------------------------------------
__global__ __launch_bounds__(256) void head_kernel(const char* __restrict__ ws,
    const float* __restrict__ bd0, const float* __restrict__ bd1,
    const float* __restrict__ bout, float* __restrict__ out)
{
    const __hip_bfloat16* y1g = (const __hip_bfloat16*)(ws + O_Y1G);
    const float* Wd0T  = (const float*)(ws + O_WD0T);
    const float* Wd1T  = (const float*)(ws + O_WD1T);
    const float* WoutT = (const float*)(ws + O_WOUT);

    __shared__ float buf0[16][256];
    __shared__ float buf1[16][256];
    const int row0 = blockIdx.x * 16;
    const int tid = threadIdx.x;

#pragma unroll
    for (int i = 0; i < 16; ++i) {
        int r = row0 + i;
        int b = r >> 11, t = r & 2047;
        buf0[i][tid] = __bfloat162float(y1g[(size_t)(t*32 + b)*256 + tid]);
    }
    __syncthreads();

    {   // stage 1: Linear+ReLU
        float acc[16];
        float bv = bd0[tid];
#pragma unroll
        for (int r = 0; r < 16; ++r) acc[r] = bv;
        for (int h = 0; h < 256; ++h) {
            float w = Wd0T[h*256 + tid];
#pragma unroll
            for (int r = 0; r < 16; ++r) acc[r] += w * buf0[r][h];
        }
        __syncthreads();
#pragma unroll
        for (int r = 0; r < 16; ++r) buf1[r][tid] = fmaxf(acc[r], 0.0f);
    }
    __syncthreads();

    {   // stage 2: Linear+ReLU
        float acc[16];
        float bv = bd1[tid];
#pragma unroll
        for (int r = 0; r < 16; ++r) acc[r] = bv;
        for (int h = 0; h < 256; ++h) {
            float w = Wd1T[h*256 + tid];
#pragma unroll
            for (int r = 0; r < 16; ++r) acc[r] += w * buf1[r][h];
        }
        __syncthreads();
#pragma unroll
        for (int r = 0; r < 16; ++r) buf0[r][tid] = fmaxf(acc[r], 0.0f);
    }
    __syncthreads();

    {   // stage 3: output Linear
        const int o = tid & 31;
        const int rr = tid >> 5;
        float a0 = bout[o], a1 = bout[o];
        for (int h = 0; h < 256; ++h) {
            float w = WoutT[h*32 + o];
            a0 += w * buf0[rr*2 + 0][h];
            a1 += w * buf0[rr*2 + 1][h];
        }
        out[(size_t)(row0 + rr*2 + 0)*32 + o] = a0;
        out[(size_t)(row0 + rr*2 + 1)*32 + o] = a1;
    }
}

// ---------------------------------------------------------------------------
extern "C" void kernel_launch(void* const* d_in, const int* in_sizes, int n_in,
                              void* d_out, int out_size, void* d_ws, size_t ws_size,
                              hipStream_t stream) {
    const float* x    = (const float*)d_in[0];
    const float* h0   = (const float*)d_in[1];
    const float* c0   = (const float*)d_in[2];
    const float* Wih0 = (const float*)d_in[3];
    const float* Whh0 = (const float*)d_in[4];
    const float* bih0 = (const float*)d_in[5];
    const float* bhh0 = (const float*)d_in[6];
    const float* Wih1 = (const float*)d_in[7];
    const float* Whh1 = (const float*)d_in[8];
    const float* bih1 = (const float*)d_in[9];
    const float* bhh1 = (const float*)d_in[10];
    const float* Wd0  = (const float*)d_in[11];
    const float* bd0  = (const float*)d_in[12];
    const float* Wd1  = (const float*)d_in[13];
    const float* bd1  = (const float*)d_in[14];
    const float* Wout = (const float*)d_in[15];
    const float* bout = (const float*)d_in[16];

    char* ws = (char*)d_ws;
    float* out = (float*)d_out;

    prep_kernel<<<20268, 256, 0, stream>>>(x, Wih0, Whh0, bih0, bhh0,
                                           Wih1, Whh1, bih1, bhh1,
                                           Wd0, Wd1, Wout, ws);
    lstm_fused<<<4, 1024, 0, stream>>>(ws, h0, c0, out);
    head_kernel<<<4096, 256, 0, stream>>>(ws, bd0, bd1, bout, out);
}

// Round 8
// 12076.791 us; speedup vs baseline: 4.7053x; 4.7053x over previous
//
#include <hip/hip_runtime.h>
#include <hip/hip_bf16.h>
#include <cstddef>
#include <cstdint>

// B=32, T=2048, D=64, H=256, O=32, 4H=1024
#define BB 32
#define TT 2048
#define DD 64
#define HH 256
#define OO 32
#define NBLK 8   // blocks per layer

#define OUT_ELEMS (BB*TT*OO)
#define HN_OFF OUT_ELEMS
#define CN_OFF (HN_OFF + 2*BB*HH)

// ---------------- workspace byte offsets ----------------
#define O_XBF   ((size_t)0)                     // x bf16 [T][B][64]
#define O_H0    ((size_t)8388608)               // h0buf bf16 [2049][32][256]
#define O_XH1   ((size_t)41959424)              // xh1 bf16 [2049][32][512]
#define O_WP0   ((size_t)109101056)             // Wperm0 bf16 [1024][320]
#define O_WP1   ((size_t)109756416)             // Wperm1 bf16 [1024][512]
#define O_B0    ((size_t)110804992)             // bias0 f32 [1024]
#define O_B1    ((size_t)110809088)             // bias1 f32 [1024]
#define O_WD0T  ((size_t)110813184)             // [256][256] f32 transposed
#define O_WD1T  ((size_t)111075328)
#define O_WOUT  ((size_t)111337472)             // [256][32] f32
#define O_D0    ((size_t)111370240)             // flags layer0: int[8]
#define O_D1    (O_D0 + 256)                    // flags layer1: int[8]
#define DONE_IDX 128                            // done counter: int[(O_D0)]+128
// prep zeroes 16KB of ints starting at O_D0 (covers flags + done)

typedef short short8 __attribute__((ext_vector_type(8)));
typedef float f32x4 __attribute__((ext_vector_type(4)));

__device__ __forceinline__ float sigm_(float x){ return 1.0f/(1.0f+__expf(-x)); }
__device__ __forceinline__ float tanhf_(float x){
    float xc = fminf(fmaxf(x, -15.0f), 15.0f);
    float e = __expf(2.0f*xc);
    return (e-1.0f)/(e+1.0f);
}
__device__ __forceinline__ unsigned short f2bf(float f){
    __hip_bfloat16 h = __float2bfloat16(f);
    return *reinterpret_cast<unsigned short*>(&h);
}
__device__ __forceinline__ unsigned int pack2(float a, float b){
    return (unsigned int)f2bf(a) | ((unsigned int)f2bf(b) << 16);
}
__device__ __forceinline__ short8 ld8(const unsigned short* p){
    return *reinterpret_cast<const short8*>(p);
}

// Single-poller primitives (proven rounds 4-5): wave 0 only; one LLC line per
// round; s_sleep backoff; capped so bugs fail validation instead of hanging.
__device__ __forceinline__ void pollLine(const int* flags, int tgt, int lane){
    int it = 0;
    while (true) {
        int v = tgt;
        if (lane < NBLK)
            v = __hip_atomic_load(flags + lane, __ATOMIC_RELAXED, __HIP_MEMORY_SCOPE_AGENT);
        if (__all(v >= tgt)) break;
        __builtin_amdgcn_s_sleep(1);
        if (++it > (1<<16)) break;
    }
    asm volatile("" ::: "memory");
}

__device__ __forceinline__ void pollTwo(const int* f0, int t0,
                                        const int* f1, int t1, int lane){
    const int* p = (lane < 8) ? (f0 + lane) : (f1 + (lane - 8));
    const int tgt = (lane < 8) ? t0 : t1;
    int it = 0;
    while (true) {
        int v = tgt;
        if (lane < 16)
            v = __hip_atomic_load(p, __ATOMIC_RELAXED, __HIP_MEMORY_SCOPE_AGENT);
        if (__all(v >= tgt)) break;
        __builtin_amdgcn_s_sleep(1);
        if (++it > (1<<16)) break;
    }
    asm volatile("" ::: "memory");
}

// ---------------------------------------------------------------------------
// Prep (identical to rounds 4-5).
// ---------------------------------------------------------------------------
__global__ void prep_kernel(const float* __restrict__ x, const float* __restrict__ h0,
    const float* __restrict__ Wih0, const float* __restrict__ Whh0,
    const float* __restrict__ bih0, const float* __restrict__ bhh0,
    const float* __restrict__ Wih1, const float* __restrict__ Whh1,
    const float* __restrict__ bih1, const float* __restrict__ bhh1,
    const float* __restrict__ Wd0, const float* __restrict__ Wd1,
    const float* __restrict__ Wout, char* __restrict__ ws)
{
    int i = blockIdx.x*256 + threadIdx.x;
    if (i < 4194304) {  // x [B][T][D] -> xbf2 [T][B][D] bf16
        int t = i >> 11, rem = i & 2047, b = rem >> 6, d = rem & 63;
        ((unsigned short*)(ws+O_XBF))[i] = f2bf(x[(size_t)b*131072 + t*64 + d]);
        return;
    }
    i -= 4194304;
    if (i < 327680) {   // Wperm0 [1024][320]
        int R = i / 320, k = i - R*320;
        int lrow = R & 15, s = (R>>4)&1, hr = (R>>5)&3, jj = R>>7;
        int gate = 2*s + (lrow>>3);
        int h = 32*jj + 8*hr + (lrow&7);
        int src = 256*gate + h;
        float v = (k < 64) ? Wih0[src*64 + k] : Whh0[src*256 + (k-64)];
        ((unsigned short*)(ws+O_WP0))[i] = f2bf(v);
        return;
    }
    i -= 327680;
    if (i < 524288) {   // Wperm1 [1024][512]
        int R = i >> 9, k = i & 511;
        int lrow = R & 15, s = (R>>4)&1, hr = (R>>5)&3, jj = R>>7;
        int gate = 2*s + (lrow>>3);
        int h = 32*jj + 8*hr + (lrow&7);
        int src = 256*gate + h;
        float v = (k < 256) ? Wih1[src*256 + k] : Whh1[src*256 + (k-256)];
        ((unsigned short*)(ws+O_WP1))[i] = f2bf(v);
        return;
    }
    i -= 524288;
    if (i < 1024) { ((float*)(ws+O_B0))[i] = bih0[i] + bhh0[i]; return; }
    i -= 1024;
    if (i < 1024) { ((float*)(ws+O_B1))[i] = bih1[i] + bhh1[i]; return; }
    i -= 1024;
    if (i < 8192) { ((unsigned short*)(ws+O_H0))[i] = f2bf(h0[i]); return; }   // h0buf[0]
    i -= 8192;
    if (i < 8192) {     // xh1[0][b][256+h] = h0[1][b][h]
        int b = i >> 8, h = i & 255;
        ((unsigned short*)(ws+O_XH1))[b*512 + 256 + h] = f2bf(h0[8192 + i]);
        return;
    }
    i -= 8192;
    if (i < 65536) { int o = i & 255, h = i >> 8; ((float*)(ws+O_WD0T))[i] = Wd0[o*256 + h]; return; }
    i -= 65536;
    if (i < 65536) { int o = i & 255, h = i >> 8; ((float*)(ws+O_WD1T))[i] = Wd1[o*256 + h]; return; }
    i -= 65536;
    if (i < 8192) { int o = i & 31, h = i >> 5; ((float*)(ws+O_WOUT))[i] = Wout[o*256 + h]; return; }
    i -= 8192;
    if (i < 4096) { ((int*)(ws+O_D0))[i] = 0; return; }   // flags + done
}

// ---------------------------------------------------------------------------
// Persistent LSTM worker body (byte-identical logic to round 5, 12.1ms PASS).
// ---------------------------------------------------------------------------
template<int L>
__device__ void lstm_body(int j, char* ws, const float* __restrict__ c0_in,
                          float* __restrict__ out)
{
    constexpr int KK  = L ? 512 : 320;
    constexpr int NKT = KK / 32;

    const int tid  = threadIdx.x;
    const int wv   = tid >> 6;
    const int lane = tid & 63;
    const int bh   = wv >> 2;
    const int hr   = wv & 3;
    const int lrow = lane & 15;
    const int q    = lane >> 4;
    const int koff = q * 8;
    const int qe   = q & 1;
    const int fb   = bh*16 + lrow;
    const int hbase= 32*j + 8*hr + 4*qe;
    const bool lo  = (lane < 32);

    const unsigned short* Wp = (const unsigned short*)(ws + (L ? O_WP1 : O_WP0));
    const float* bias = (const float*)(ws + (L ? O_B1 : O_B0));

    const int wavebase = (j*4 + hr) * 32;
    short8 a0[NKT], a1[NKT];
#pragma unroll
    for (int kk = 0; kk < NKT; ++kk) {
        a0[kk] = ld8(Wp + (size_t)(wavebase +      lrow)*KK + kk*32 + koff);
        a1[kk] = ld8(Wp + (size_t)(wavebase + 16 + lrow)*KK + kk*32 + koff);
    }

    float bi[4], bf_[4], bg[4], bo[4], c[4], hv[4];
#pragma unroll
    for (int r = 0; r < 4; ++r) {
        int hg = hbase + r;
        bi[r] = bias[hg];       bf_[r] = bias[256+hg];
        bg[r] = bias[512+hg];   bo[r]  = bias[768+hg];
        c[r]  = c0_in[(size_t)L*8192 + fb*256 + hg];
        hv[r] = 0.f;
    }

    int* flags0 = (int*)(ws + O_D0);
    int* flags1 = (int*)(ws + O_D1);
    int* myflag = (L ? flags1 : flags0) + j;

    const unsigned short* xb = (const unsigned short*)(ws + O_XBF) + fb*64  + koff;
    const unsigned short* hb = (const unsigned short*)(ws + O_H0)  + fb*256 + koff;
    const unsigned short* xh = (const unsigned short*)(ws + O_XH1) + fb*512 + koff;

    unsigned long long* stA;
    unsigned long long* stB = nullptr;
    if (L == 0) {
        stA = (unsigned long long*)((unsigned short*)(ws + O_H0)  + (size_t)8192 + fb*256 + hbase);
        stB = (unsigned long long*)((unsigned short*)(ws + O_XH1) + (size_t)fb*512 + hbase);
    } else {
        stA = (unsigned long long*)((unsigned short*)(ws + O_XH1) + (size_t)16384 + fb*512 + 256 + hbase);
    }

    for (int t = 0; t < TT; ++t) {
        f32x4 A0 = {0.f,0.f,0.f,0.f}, A1 = {0.f,0.f,0.f,0.f};

        if (L == 0) {
            short8 bx0 = ld8(xb), bx1 = ld8(xb + 32);
            A0 = __builtin_amdgcn_mfma_f32_16x16x32_bf16(a0[0], bx0, A0, 0,0,0);
            A1 = __builtin_amdgcn_mfma_f32_16x16x32_bf16(a1[0], bx0, A1, 0,0,0);
            A0 = __builtin_amdgcn_mfma_f32_16x16x32_bf16(a0[1], bx1, A0, 0,0,0);
            A1 = __builtin_amdgcn_mfma_f32_16x16x32_bf16(a1[1], bx1, A1, 0,0,0);

            if (wv == 0) pollLine(flags0, t, lane);
            __syncthreads();

            short8 b[8];
#pragma unroll
            for (int kk = 0; kk < 8; ++kk) b[kk] = ld8(hb + 32*kk);
#pragma unroll
            for (int kk = 0; kk < 8; ++kk) {
                A0 = __builtin_amdgcn_mfma_f32_16x16x32_bf16(a0[2+kk], b[kk], A0, 0,0,0);
                A1 = __builtin_amdgcn_mfma_f32_16x16x32_bf16(a1[2+kk], b[kk], A1, 0,0,0);
            }
        } else {
            if (wv == 0) pollTwo(flags0, t+1, flags1, t, lane);
            __syncthreads();

            short8 b[8];
#pragma unroll
            for (int kk = 0; kk < 8; ++kk) b[kk] = ld8(xh + 32*kk);
#pragma unroll
            for (int kk = 0; kk < 8; ++kk) {
                A0 = __builtin_amdgcn_mfma_f32_16x16x32_bf16(a0[kk], b[kk], A0, 0,0,0);
                A1 = __builtin_amdgcn_mfma_f32_16x16x32_bf16(a1[kk], b[kk], A1, 0,0,0);
            }
#pragma unroll
            for (int kk = 0; kk < 8; ++kk) b[kk] = ld8(xh + 256 + 32*kk);
#pragma unroll
            for (int kk = 0; kk < 8; ++kk) {
                A0 = __builtin_amdgcn_mfma_f32_16x16x32_bf16(a0[8+kk], b[kk], A0, 0,0,0);
                A1 = __builtin_amdgcn_mfma_f32_16x16x32_bf16(a1[8+kk], b[kk], A1, 0,0,0);
            }
        }

#pragma unroll
        for (int r = 0; r < 4; ++r) {
            float x0 = A0[r], y0 = __shfl_xor(x0, 32, 64);
            float x1 = A1[r], y1 = __shfl_xor(x1, 32, 64);
            float gi = (lo ? x0 : y0) + bi[r];
            float gf = (lo ? y0 : x0) + bf_[r];
            float gg = (lo ? x1 : y1) + bg[r];
            float go = (lo ? y1 : x1) + bo[r];
            float iv = sigm_(gi), fv = sigm_(gf), gv = tanhf_(gg), ov = sigm_(go);
            c[r]  = fv*c[r] + iv*gv;
            hv[r] = ov * tanhf_(c[r]);
        }

        unsigned long long w =
            (unsigned long long)pack2(hv[0], hv[1]) |
            ((unsigned long long)pack2(hv[2], hv[3]) << 32);

        if (L == 0) {
            if (lo) __hip_atomic_store(stA, w, __ATOMIC_RELAXED, __HIP_MEMORY_SCOPE_AGENT);
            else    __hip_atomic_store(stB, w, __ATOMIC_RELAXED, __HIP_MEMORY_SCOPE_AGENT);
        } else {
            if (lo) __hip_atomic_store(stA, w, __ATOMIC_RELAXED, __HIP_MEMORY_SCOPE_AGENT);
        }

        __syncthreads();
        if (tid == 0)
            __hip_atomic_store(myflag, t+1, __ATOMIC_RELAXED, __HIP_MEMORY_SCOPE_AGENT);

        xb += 2048; hb += 8192; xh += 16384;
        stA += (L ? 4096 : 2048);
        if (L == 0) stB += 4096;
    }

    if (lo) {
#pragma unroll
        for (int r = 0; r < 4; ++r) {
            out[HN_OFF + (size_t)L*8192 + fb*256 + hbase + r] = hv[r];
            out[CN_OFF + (size_t)L*8192 + fb*256 + hbase + r] = c[r];
        }
    }
}

// ---------------------------------------------------------------------------
// Mega-kernel: blocks 0..15 = round-5 workers; blocks 16..255 = clock-keepers
// (pure-VALU FMA spin, zero memory traffic except a 1-per-~4Kcy done check).
// Keepers write nothing -> output identical to round 5.
// ---------------------------------------------------------------------------
__global__ __launch_bounds__(512, 2) void lstm_fused(char* ws,
                                                     const float* __restrict__ c0_in,
                                                     float* __restrict__ out)
{
    const int blk = blockIdx.x;
    int* done = (int*)(ws + O_D0) + DONE_IDX;

    if (blk < NBLK) {
        lstm_body<0>(blk, ws, c0_in, out);
        if (threadIdx.x == 0)
            __hip_atomic_fetch_add(done, 1, __ATOMIC_RELAXED, __HIP_MEMORY_SCOPE_AGENT);
        return;
    }
    if (blk < 2*NBLK) {
        lstm_body<1>(blk - NBLK, ws, c0_in, out);
        if (threadIdx.x == 0)
            __hip_atomic_fetch_add(done, 1, __ATOMIC_RELAXED, __HIP_MEMORY_SCOPE_AGENT);
        return;
    }

    // ---- clock-keeper: 4 independent FMA chains, check done every chunk ----
    __shared__ int sh;
    float c0 = 1.0f + (float)threadIdx.x;
    float c1 = 2.0f + (float)(threadIdx.x & 7);
    float c2 = 3.0f;
    float c3 = 4.0f;
    for (int it = 0; it < (1<<20); ++it) {
#pragma unroll 16
        for (int k = 0; k < 256; ++k) {
            c0 = __builtin_fmaf(c0, 1.0000001f, 1e-8f);
            c1 = __builtin_fmaf(c1, 0.9999999f, 1e-8f);
            c2 = __builtin_fmaf(c2, 1.0000002f, 2e-8f);
            c3 = __builtin_fmaf(c3, 0.9999998f, 2e-8f);
        }
        if (threadIdx.x == 0)
            sh = __hip_atomic_load(done, __ATOMIC_RELAXED, __HIP_MEMORY_SCOPE_AGENT);
        __syncthreads();
        int d = sh;
        __syncthreads();   // protect sh before next write
        if (d >= 2*NBLK) break;
    }
    asm volatile("" :: "v"(c0), "v"(c1), "v"(c2), "v"(c3));  // keep chains live
}

// ---------------------------------------------------------------------------
// Fused dense head (identical to round 5).
// ---------------------------------------------------------------------------
__global__ __launch_bounds__(256) void head_kernel(const char* __restrict__ ws,
    const float* __restrict__ bd0, const float* __restrict__ bd1,
    const float* __restrict__ bout, float* __restrict__ out)
{
    const __hip_bfloat16* xh1 = (const __hip_bfloat16*)(ws + O_XH1);
    const float* Wd0T  = (const float*)(ws + O_WD0T);
    const float* Wd1T  = (const float*)(ws + O_WD1T);
    const float* WoutT = (const float*)(ws + O_WOUT);

    __shared__ float buf0[16][256];
    __shared__ float buf1[16][256];
    const int row0 = blockIdx.x * 16;
    const int tid = threadIdx.x;

#pragma unroll
    for (int i = 0; i < 16; ++i) {
        int r = row0 + i;
        int b = r >> 11, t = r & 2047;
        buf0[i][tid] = __bfloat162float(xh1[(size_t)(t+1)*16384 + b*512 + 256 + tid]);
    }
    __syncthreads();

    {   // stage 1: Linear+ReLU
        float acc[16];
        float bv = bd0[tid];
#pragma unroll
        for (int r = 0; r < 16; ++r) acc[r] = bv;
        for (int h = 0; h < 256; ++h) {
            float w = Wd0T[h*256 + tid];
#pragma unroll
            for (int r = 0; r < 16; ++r) acc[r] += w * buf0[r][h];
        }
        __syncthreads();
#pragma unroll
        for (int r = 0; r < 16; ++r) buf1[r][tid] = fmaxf(acc[r], 0.0f);
    }
    __syncthreads();

    {   // stage 2: Linear+ReLU
        float acc[16];
        float bv = bd1[tid];
#pragma unroll
        for (int r = 0; r < 16; ++r) acc[r] = bv;
        for (int h = 0; h < 256; ++h) {
            float w = Wd1T[h*256 + tid];
#pragma unroll
            for (int r = 0; r < 16; ++r) acc[r] += w * buf1[r][h];
        }
        __syncthreads();
#pragma unroll
        for (int r = 0; r < 16; ++r) buf0[r][tid] = fmaxf(acc[r], 0.0f);
    }
    __syncthreads();

    {   // stage 3: output Linear
        const int o = tid & 31;
        const int rr = tid >> 5;
        float a0 = bout[o], a1 = bout[o];
        for (int h = 0; h < 256; ++h) {
            float w = WoutT[h*32 + o];
            a0 += w * buf0[rr*2 + 0][h];
            a1 += w * buf0[rr*2 + 1][h];
        }
        out[(size_t)(row0 + rr*2 + 0)*32 + o] = a0;
        out[(size_t)(row0 + rr*2 + 1)*32 + o] = a1;
    }
}

// ---------------------------------------------------------------------------
extern "C" void kernel_launch(void* const* d_in, const int* in_sizes, int n_in,
                              void* d_out, int out_size, void* d_ws, size_t ws_size,
                              hipStream_t stream) {
    const float* x    = (const float*)d_in[0];
    const float* h0   = (const float*)d_in[1];
    const float* c0   = (const float*)d_in[2];
    const float* Wih0 = (const float*)d_in[3];
    const float* Whh0 = (const float*)d_in[4];
    const float* bih0 = (const float*)d_in[5];
    const float* bhh0 = (const float*)d_in[6];
    const float* Wih1 = (const float*)d_in[7];
    const float* Whh1 = (const float*)d_in[8];
    const float* bih1 = (const float*)d_in[9];
    const float* bhh1 = (const float*)d_in[10];
    const float* Wd0  = (const float*)d_in[11];
    const float* bd0  = (const float*)d_in[12];
    const float* Wd1  = (const float*)d_in[13];
    const float* bd1  = (const float*)d_in[14];
    const float* Wout = (const float*)d_in[15];
    const float* bout = (const float*)d_in[16];

    char* ws = (char*)d_ws;
    float* out = (float*)d_out;

    prep_kernel<<<20344, 256, 0, stream>>>(x, h0, Wih0, Whh0, bih0, bhh0,
                                           Wih1, Whh1, bih1, bhh1,
                                           Wd0, Wd1, Wout, ws);
    lstm_fused<<<256, 512, 0, stream>>>(ws, c0, out);
    head_kernel<<<4096, 256, 0, stream>>>(ws, bd0, bd1, bout, out);
}